// Round 6
// baseline (65.815 us; speedup 1.0000x reference)
//
#include <hip/hip_runtime.h>
#include <math.h>

#define P 7
#define PP (P * P)
#define C 256
#define H 64
#define W 64
#define S (H * W)
#define R_MAX 1024

#define CH 32                 // channels per fused pool block
#define NCG (C / CH)          // 8 channel-groups per roi
#define ITEMS (PP * (CH / 4)) // 392 float4 work items per block
#define LDS_PAD (PP + 1)      // 50

// ---------------------------------------------------------------------------
// Transpose [N, C, S] -> [N, S, C], tiled 32x32 through LDS
// ---------------------------------------------------------------------------
#define TS 32
__global__ __launch_bounds__(256) void transpose_kernel(
    const float* __restrict__ in, float* __restrict__ outT)
{
    __shared__ float tile[TS][TS + 1];
    const int b  = blockIdx.z;
    const int s0 = blockIdx.x * TS;
    const int c0 = blockIdx.y * TS;
    const int tx = threadIdx.x;  // 0..31
    const int ty = threadIdx.y;  // 0..7

    const float* ip = in + ((size_t)b * C + c0) * S + s0;
    #pragma unroll
    for (int k = 0; k < 4; ++k)
        tile[ty + 8 * k][tx] = ip[(size_t)(ty + 8 * k) * S + tx];

    __syncthreads();

    float* op = outT + ((size_t)b * S + s0) * C + c0;
    #pragma unroll
    for (int k = 0; k < 4; ++k)
        op[(size_t)(ty + 8 * k) * C + tx] = tile[tx][ty + 8 * k];
}

// ---------------------------------------------------------------------------
// Stable counting-sort of rois by image id -> perm (deterministic)
// ---------------------------------------------------------------------------
__global__ __launch_bounds__(256) void bucket_kernel(
    const float* __restrict__ rois, int* __restrict__ perm, int R)
{
    __shared__ int bimg[R_MAX];
    for (int t = threadIdx.x; t < R; t += blockDim.x)
        bimg[t] = (int)rois[(size_t)t * 5];
    __syncthreads();
    for (int t = threadIdx.x; t < R; t += blockDim.x) {
        const int myb = bimg[t];
        int pos = 0;
        for (int k = 0; k < R; ++k) {
            const int bk = bimg[k];
            pos += (bk < myb) || (bk == myb && k < t);
        }
        perm[pos] = t;
    }
}

// ---------------------------------------------------------------------------
// Fused RoI max-pool + output reorder.
// Block = (rslot, channel-group of 32). 64 threads, 392 float4 bin-max items
// (49 cells x 8 channel-quads), staged in LDS [32][50], then written to
// out[r, cbase..cbase+31, 0..48] as 1568 contiguous floats (float4 stores).
// Chunked XCD swizzle + image-sorted rois keep each XCD on ~one image (L2-fit).
// ---------------------------------------------------------------------------
__global__ __launch_bounds__(64) void roi_pool_fused_kernel(
    const float* __restrict__ ft,    // [N, H, W, C]
    const float* __restrict__ rois,
    const int*   __restrict__ perm,
    float* __restrict__ out)         // [R, C, P, P]
{
    __shared__ float lds[CH * LDS_PAD];   // 6.4 KB

    const int l   = blockIdx.x;
    const int nwg = gridDim.x;            // R * NCG, always % 8 == 0
    const int work  = (l & 7) * (nwg >> 3) + (l >> 3);   // bijective chunk swizzle
    const int rslot = work / NCG;
    const int cg    = work % NCG;
    const int t     = threadIdx.x;
    const int cbase = cg * CH;

    const int r = perm[rslot];
    const float* roi = rois + (size_t)r * 5;
    const int b = (int)roi[0];
    // jnp.round is half-to-even; rintf matches (RNE); *2^-5 scale is exact.
    int x0 = (int)rintf(roi[1] * 0.03125f);
    int y0 = (int)rintf(roi[2] * 0.03125f);
    int x1 = (int)rintf(roi[3] * 0.03125f);
    int y1 = (int)rintf(roi[4] * 0.03125f);
    x0 = min(max(x0, 0), W - 1);
    y0 = min(max(y0, 0), H - 1);
    x1 = min(max(x1, 0), W - 1);
    y1 = min(max(y1, 0), H - 1);

    const bool valid = (x0 < x1) && (y0 < y1);

    if (valid) {
        const int Lh = x1 - x0;  // x-range bins the H axis (reference quirk)
        const int Lw = y1 - y0;  // y-range bins the W axis
        #pragma unroll
        for (int k = 0; k < 7; ++k) {
            const int item = t + 64 * k;
            if (item < ITEMS) {
                const int cell = item >> 3;      // 0..48
                const int q    = item & 7;       // channel quad within group
                const int i    = cell / P;
                const int j    = cell - P * i;

                const int hs = x0 + (i * Lh) / P;
                const int he = x0 + ((i + 1) * Lh + (P - 1)) / P;
                const int ws = y0 + (j * Lw) / P;
                const int we = y0 + ((j + 1) * Lw + (P - 1)) / P;
                const int bh = he - hs;          // >= 1
                const int bw = we - ws;          // >= 1

                const float* base = ft + (((size_t)b * H + hs) * W + ws) * C + cbase + q * 4;

                float mx = -INFINITY, my = -INFINITY, mz = -INFINITY, mw = -INFINITY;
                for (int h = 0; h < bh; h += 2) {
                    const int h2 = min(h + 1, bh - 1);   // clamp: dup row no-op for max
                    const float* r0 = base + (size_t)h  * (W * C);
                    const float* r1 = base + (size_t)h2 * (W * C);
                    for (int w = 0; w < bw; w += 2) {
                        const int w2 = min(w + 1, bw - 1); // clamp: dup col no-op
                        const float4 a  = *(const float4*)(r0 + (size_t)w  * C);
                        const float4 bb = *(const float4*)(r0 + (size_t)w2 * C);
                        const float4 cc = *(const float4*)(r1 + (size_t)w  * C);
                        const float4 dd = *(const float4*)(r1 + (size_t)w2 * C);
                        mx = fmaxf(fmaxf(fmaxf(mx, a.x), fmaxf(bb.x, cc.x)), dd.x);
                        my = fmaxf(fmaxf(fmaxf(my, a.y), fmaxf(bb.y, cc.y)), dd.y);
                        mz = fmaxf(fmaxf(fmaxf(mz, a.z), fmaxf(bb.z, cc.z)), dd.z);
                        mw = fmaxf(fmaxf(fmaxf(mw, a.w), fmaxf(bb.w, cc.w)), dd.w);
                    }
                }
                const int cl = q * 4;
                lds[(cl + 0) * LDS_PAD + cell] = mx;
                lds[(cl + 1) * LDS_PAD + cell] = my;
                lds[(cl + 2) * LDS_PAD + cell] = mz;
                lds[(cl + 3) * LDS_PAD + cell] = mw;
            }
        }
    } else {
        #pragma unroll
        for (int k = 0; k < 7; ++k) {
            const int item = t + 64 * k;
            if (item < ITEMS) {
                const int cell = item >> 3;
                const int cl   = (item & 7) * 4;
                lds[(cl + 0) * LDS_PAD + cell] = 0.0f;
                lds[(cl + 1) * LDS_PAD + cell] = 0.0f;
                lds[(cl + 2) * LDS_PAD + cell] = 0.0f;
                lds[(cl + 3) * LDS_PAD + cell] = 0.0f;
            }
        }
    }

    __syncthreads();

    // Write out[r, cbase..cbase+CH-1, 0..PP-1]: 1568 contiguous floats.
    float* dst = out + ((size_t)r * C + cbase) * PP;
    #pragma unroll
    for (int k = 0; k < 7; ++k) {
        const int fq = t + 64 * k;
        if (fq < ITEMS) {
            float v[4];
            #pragma unroll
            for (int m = 0; m < 4; ++m) {
                const int idx  = 4 * fq + m;
                const int cl   = idx / PP;
                const int cell = idx - PP * cl;
                v[m] = lds[cl * LDS_PAD + cell];
            }
            *(float4*)(dst + 4 * fq) = make_float4(v[0], v[1], v[2], v[3]);
        }
    }
}

// ---------------------------------------------------------------------------
// Fallback tier 1: pool with direct strided out writes (no perm/ws2 needed)
// ---------------------------------------------------------------------------
__global__ __launch_bounds__(64) void roi_pool_cell_direct_kernel(
    const float* __restrict__ ft, const float* __restrict__ rois,
    float* __restrict__ out)
{
    const int bid = blockIdx.x;
    const int r   = bid / PP;
    const int rem = bid % PP;
    const int i   = rem / P;
    const int j   = rem % P;
    const int c4  = threadIdx.x;

    const float* roi = rois + (size_t)r * 5;
    const int b = (int)roi[0];
    int x0 = (int)rintf(roi[1] * 0.03125f);
    int y0 = (int)rintf(roi[2] * 0.03125f);
    int x1 = (int)rintf(roi[3] * 0.03125f);
    int y1 = (int)rintf(roi[4] * 0.03125f);
    x0 = min(max(x0, 0), W - 1);
    y0 = min(max(y0, 0), H - 1);
    x1 = min(max(x1, 0), W - 1);
    y1 = min(max(y1, 0), H - 1);

    float* o = out + (((size_t)r * C + c4 * 4) * P + i) * P + j;
    if (!((x0 < x1) && (y0 < y1))) {
        o[0] = 0.0f; o[PP] = 0.0f; o[2 * PP] = 0.0f; o[3 * PP] = 0.0f;
        return;
    }
    const int Lh = x1 - x0, Lw = y1 - y0;
    const int hs = x0 + (i * Lh) / P;
    const int he = x0 + ((i + 1) * Lh + (P - 1)) / P;
    const int ws = y0 + (j * Lw) / P;
    const int we = y0 + ((j + 1) * Lw + (P - 1)) / P;
    const int bh = he - hs, bw = we - ws;
    const float* base = ft + (((size_t)b * H + hs) * W + ws) * C + c4 * 4;
    float mx = -INFINITY, my = -INFINITY, mz = -INFINITY, mw = -INFINITY;
    for (int h = 0; h < bh; h += 2) {
        const int h2 = min(h + 1, bh - 1);
        const float* r0 = base + (size_t)h  * (W * C);
        const float* r1 = base + (size_t)h2 * (W * C);
        for (int w = 0; w < bw; w += 2) {
            const int w2 = min(w + 1, bw - 1);
            const float4 a  = *(const float4*)(r0 + (size_t)w  * C);
            const float4 bb = *(const float4*)(r0 + (size_t)w2 * C);
            const float4 cc = *(const float4*)(r1 + (size_t)w  * C);
            const float4 dd = *(const float4*)(r1 + (size_t)w2 * C);
            mx = fmaxf(fmaxf(fmaxf(mx, a.x), fmaxf(bb.x, cc.x)), dd.x);
            my = fmaxf(fmaxf(fmaxf(my, a.y), fmaxf(bb.y, cc.y)), dd.y);
            mz = fmaxf(fmaxf(fmaxf(mz, a.z), fmaxf(bb.z, cc.z)), dd.z);
            mw = fmaxf(fmaxf(fmaxf(mw, a.w), fmaxf(bb.w, cc.w)), dd.w);
        }
    }
    o[0] = mx; o[PP] = my; o[2 * PP] = mz; o[3 * PP] = mw;
}

// ---------------------------------------------------------------------------
// Fallback tier 2: no workspace
// ---------------------------------------------------------------------------
__global__ __launch_bounds__(256) void roi_pool_naive_kernel(
    const float* __restrict__ features, const float* __restrict__ rois,
    float* __restrict__ out)
{
    const int rb = blockIdx.x;
    const int r = rb / P;
    const int i = rb % P;
    const int c = threadIdx.x;

    const float* roi = rois + (size_t)r * 5;
    const int b = (int)roi[0];
    int x0 = (int)rintf(roi[1] * 0.03125f);
    int y0 = (int)rintf(roi[2] * 0.03125f);
    int x1 = (int)rintf(roi[3] * 0.03125f);
    int y1 = (int)rintf(roi[4] * 0.03125f);
    x0 = min(max(x0, 0), W - 1);
    y0 = min(max(y0, 0), H - 1);
    x1 = min(max(x1, 0), W - 1);
    y1 = min(max(y1, 0), H - 1);

    const bool valid = (x0 < x1) && (y0 < y1);
    float* o = out + (((size_t)r * C + c) * P + i) * P;
    if (!valid) {
        #pragma unroll
        for (int j = 0; j < P; ++j) o[j] = 0.0f;
        return;
    }
    const int Lh = x1 - x0, Lw = y1 - y0;
    const int hs = x0 + (i * Lh) / P;
    const int he = x0 + ((i + 1) * Lh + (P - 1)) / P;
    int ws_[P], we_[P];
    #pragma unroll
    for (int j = 0; j < P; ++j) {
        ws_[j] = y0 + (j * Lw) / P;
        we_[j] = y0 + ((j + 1) * Lw + (P - 1)) / P;
    }
    float acc[P];
    #pragma unroll
    for (int j = 0; j < P; ++j) acc[j] = -INFINITY;
    const float* f = features + (((size_t)b * C + c) * H) * W;
    for (int h = hs; h < he; ++h) {
        const float* row = f + h * W;
        #pragma unroll
        for (int j = 0; j < P; ++j) {
            float m = acc[j];
            for (int w = ws_[j]; w < we_[j]; ++w) m = fmaxf(m, row[w]);
            acc[j] = m;
        }
    }
    #pragma unroll
    for (int j = 0; j < P; ++j) o[j] = acc[j];
}

extern "C" void kernel_launch(void* const* d_in, const int* in_sizes, int n_in,
                              void* d_out, int out_size, void* d_ws, size_t ws_size,
                              hipStream_t stream)
{
    const float* features = (const float*)d_in[0];
    const float* rois     = (const float*)d_in[1];
    float* out = (float*)d_out;

    const int R = in_sizes[1] / 5;                  // 256
    const int N = in_sizes[0] / (C * S);            // 4

    const size_t ft_bytes   = (size_t)N * C * S * sizeof(float);   // 16 MB
    const size_t perm_bytes = (size_t)R * sizeof(int);
    const size_t full_need  = ft_bytes + perm_bytes;

    if (ws_size >= full_need && R <= R_MAX) {
        float* ft  = (float*)d_ws;
        int*  perm = (int*)((char*)d_ws + ft_bytes);

        dim3 tgrid(S / TS, C / TS, N);
        transpose_kernel<<<tgrid, dim3(TS, 8), 0, stream>>>(features, ft);
        bucket_kernel<<<1, 256, 0, stream>>>(rois, perm, R);
        roi_pool_fused_kernel<<<R * NCG, 64, 0, stream>>>(ft, rois, perm, out);
    } else if (ws_size >= ft_bytes) {
        float* ft = (float*)d_ws;
        dim3 tgrid(S / TS, C / TS, N);
        transpose_kernel<<<tgrid, dim3(TS, 8), 0, stream>>>(features, ft);
        roi_pool_cell_direct_kernel<<<R * PP, 64, 0, stream>>>(ft, rois, out);
    } else {
        roi_pool_naive_kernel<<<R * P, C, 0, stream>>>(features, rois, out);
    }
}

// Round 7
// 49.651 us; speedup vs baseline: 1.3256x; 1.3256x over previous
//
#include <hip/hip_runtime.h>
#include <math.h>

#define P 7
#define PP (P * P)
#define C 256
#define H 64
#define W 64
#define S (H * W)
#define R_MAX 1024

#define CH 16                 // channels per fused pool block
#define NCG (C / CH)          // 16 channel-groups per roi
#define ITEMS (PP * (CH / 4)) // 196 float4 work items per block (1 per thread)
#define LDS_PAD (PP + 1)      // 50

// ---------------------------------------------------------------------------
// Transpose [N, C, S] -> [N, S, C], tiled 32x32 through LDS
// ---------------------------------------------------------------------------
#define TS 32
__global__ __launch_bounds__(256) void transpose_kernel(
    const float* __restrict__ in, float* __restrict__ outT)
{
    __shared__ float tile[TS][TS + 1];
    const int b  = blockIdx.z;
    const int s0 = blockIdx.x * TS;
    const int c0 = blockIdx.y * TS;
    const int tx = threadIdx.x;  // 0..31
    const int ty = threadIdx.y;  // 0..7

    const float* ip = in + ((size_t)b * C + c0) * S + s0;
    #pragma unroll
    for (int k = 0; k < 4; ++k)
        tile[ty + 8 * k][tx] = ip[(size_t)(ty + 8 * k) * S + tx];

    __syncthreads();

    float* op = outT + ((size_t)b * S + s0) * C + c0;
    #pragma unroll
    for (int k = 0; k < 4; ++k)
        op[(size_t)(ty + 8 * k) * C + tx] = tile[tx][ty + 8 * k];
}

// ---------------------------------------------------------------------------
// Stable counting-sort of rois by image id -> perm (deterministic)
// ---------------------------------------------------------------------------
__global__ __launch_bounds__(256) void bucket_kernel(
    const float* __restrict__ rois, int* __restrict__ perm, int R)
{
    __shared__ int bimg[R_MAX];
    for (int t = threadIdx.x; t < R; t += blockDim.x)
        bimg[t] = (int)rois[(size_t)t * 5];
    __syncthreads();
    for (int t = threadIdx.x; t < R; t += blockDim.x) {
        const int myb = bimg[t];
        int pos = 0;
        for (int k = 0; k < R; ++k) {
            const int bk = bimg[k];
            pos += (bk < myb) || (bk == myb && k < t);
        }
        perm[pos] = t;
    }
}

// ---------------------------------------------------------------------------
// Fused RoI max-pool + output reorder, one item per thread.
// Block = (rslot, 16-channel group), 256 threads (4 waves).
// 196 items = 49 cells x 4 channel-quads; thread t<196 computes one bin-max
// (float4), stages in LDS [16][50], block then writes out[r, cbase..+15, :]
// as 3136 contiguous bytes (196 float4 stores).
// Reads: 4 adjacent lanes = 64B contiguous (full line).
// Grid R*16 = 4096 blocks = 16384 waves -> deep TLP, 1-bin chains.
// Chunked XCD swizzle + image-sorted rois keep each XCD on ~one image.
// ---------------------------------------------------------------------------
__global__ __launch_bounds__(256) void roi_pool_fused_kernel(
    const float* __restrict__ ft,    // [N, H, W, C]
    const float* __restrict__ rois,
    const int*   __restrict__ perm,
    float* __restrict__ out)         // [R, C, P, P]
{
    __shared__ float lds[CH * LDS_PAD];   // 3.2 KB

    const int l   = blockIdx.x;
    const int nwg = gridDim.x;            // R * NCG, always % 8 == 0
    const int work  = ((nwg & 7) == 0) ? ((l & 7) * (nwg >> 3) + (l >> 3)) : l;
    const int rslot = work / NCG;
    const int cg    = work % NCG;
    const int t     = threadIdx.x;
    const int cbase = cg * CH;

    const int r = perm[rslot];
    const float* roi = rois + (size_t)r * 5;
    const int b = (int)roi[0];
    // jnp.round is half-to-even; rintf matches (RNE); *2^-5 scale is exact.
    int x0 = (int)rintf(roi[1] * 0.03125f);
    int y0 = (int)rintf(roi[2] * 0.03125f);
    int x1 = (int)rintf(roi[3] * 0.03125f);
    int y1 = (int)rintf(roi[4] * 0.03125f);
    x0 = min(max(x0, 0), W - 1);
    y0 = min(max(y0, 0), H - 1);
    x1 = min(max(x1, 0), W - 1);
    y1 = min(max(y1, 0), H - 1);

    const bool valid = (x0 < x1) && (y0 < y1);

    if (t < ITEMS) {
        const int cell = t >> 2;         // 0..48
        const int q    = t & 3;          // channel quad within group
        float mx = 0.0f, my = 0.0f, mz = 0.0f, mw = 0.0f;

        if (valid) {
            const int Lh = x1 - x0;  // x-range bins the H axis (reference quirk)
            const int Lw = y1 - y0;  // y-range bins the W axis
            const int i  = cell / P;
            const int j  = cell - P * i;

            const int hs = x0 + (i * Lh) / P;
            const int he = x0 + ((i + 1) * Lh + (P - 1)) / P;
            const int ws = y0 + (j * Lw) / P;
            const int we = y0 + ((j + 1) * Lw + (P - 1)) / P;
            const int bh = he - hs;      // >= 1
            const int bw = we - ws;      // >= 1

            const float* base = ft + (((size_t)b * H + hs) * W + ws) * C + cbase + q * 4;

            mx = -INFINITY; my = -INFINITY; mz = -INFINITY; mw = -INFINITY;
            for (int h = 0; h < bh; h += 2) {
                const int h2 = min(h + 1, bh - 1);       // clamp: dup row no-op for max
                const float* r0 = base + (size_t)h  * (W * C);
                const float* r1 = base + (size_t)h2 * (W * C);
                for (int w = 0; w < bw; w += 2) {
                    const int w2 = min(w + 1, bw - 1);   // clamp: dup col no-op
                    const float4 a  = *(const float4*)(r0 + (size_t)w  * C);
                    const float4 bb = *(const float4*)(r0 + (size_t)w2 * C);
                    const float4 cc = *(const float4*)(r1 + (size_t)w  * C);
                    const float4 dd = *(const float4*)(r1 + (size_t)w2 * C);
                    mx = fmaxf(fmaxf(fmaxf(mx, a.x), fmaxf(bb.x, cc.x)), dd.x);
                    my = fmaxf(fmaxf(fmaxf(my, a.y), fmaxf(bb.y, cc.y)), dd.y);
                    mz = fmaxf(fmaxf(fmaxf(mz, a.z), fmaxf(bb.z, cc.z)), dd.z);
                    mw = fmaxf(fmaxf(fmaxf(mw, a.w), fmaxf(bb.w, cc.w)), dd.w);
                }
            }
        }

        const int cl = q * 4;
        lds[(cl + 0) * LDS_PAD + cell] = mx;
        lds[(cl + 1) * LDS_PAD + cell] = my;
        lds[(cl + 2) * LDS_PAD + cell] = mz;
        lds[(cl + 3) * LDS_PAD + cell] = mw;
    }

    __syncthreads();

    // Write out[r, cbase..cbase+CH-1, 0..PP-1]: 784 contiguous floats.
    if (t < ITEMS) {
        float v[4];
        #pragma unroll
        for (int m = 0; m < 4; ++m) {
            const int idx  = 4 * t + m;
            const int cl   = idx / PP;
            const int cell = idx - PP * cl;
            v[m] = lds[cl * LDS_PAD + cell];
        }
        float* dst = out + ((size_t)r * C + cbase) * PP;
        *(float4*)(dst + 4 * t) = make_float4(v[0], v[1], v[2], v[3]);
    }
}

// ---------------------------------------------------------------------------
// Fallback tier 1: pool with direct strided out writes (no perm needed)
// ---------------------------------------------------------------------------
__global__ __launch_bounds__(64) void roi_pool_cell_direct_kernel(
    const float* __restrict__ ft, const float* __restrict__ rois,
    float* __restrict__ out)
{
    const int bid = blockIdx.x;
    const int r   = bid / PP;
    const int rem = bid % PP;
    const int i   = rem / P;
    const int j   = rem % P;
    const int c4  = threadIdx.x;

    const float* roi = rois + (size_t)r * 5;
    const int b = (int)roi[0];
    int x0 = (int)rintf(roi[1] * 0.03125f);
    int y0 = (int)rintf(roi[2] * 0.03125f);
    int x1 = (int)rintf(roi[3] * 0.03125f);
    int y1 = (int)rintf(roi[4] * 0.03125f);
    x0 = min(max(x0, 0), W - 1);
    y0 = min(max(y0, 0), H - 1);
    x1 = min(max(x1, 0), W - 1);
    y1 = min(max(y1, 0), H - 1);

    float* o = out + (((size_t)r * C + c4 * 4) * P + i) * P + j;
    if (!((x0 < x1) && (y0 < y1))) {
        o[0] = 0.0f; o[PP] = 0.0f; o[2 * PP] = 0.0f; o[3 * PP] = 0.0f;
        return;
    }
    const int Lh = x1 - x0, Lw = y1 - y0;
    const int hs = x0 + (i * Lh) / P;
    const int he = x0 + ((i + 1) * Lh + (P - 1)) / P;
    const int ws = y0 + (j * Lw) / P;
    const int we = y0 + ((j + 1) * Lw + (P - 1)) / P;
    const int bh = he - hs, bw = we - ws;
    const float* base = ft + (((size_t)b * H + hs) * W + ws) * C + c4 * 4;
    float mx = -INFINITY, my = -INFINITY, mz = -INFINITY, mw = -INFINITY;
    for (int h = 0; h < bh; h += 2) {
        const int h2 = min(h + 1, bh - 1);
        const float* r0 = base + (size_t)h  * (W * C);
        const float* r1 = base + (size_t)h2 * (W * C);
        for (int w = 0; w < bw; w += 2) {
            const int w2 = min(w + 1, bw - 1);
            const float4 a  = *(const float4*)(r0 + (size_t)w  * C);
            const float4 bb = *(const float4*)(r0 + (size_t)w2 * C);
            const float4 cc = *(const float4*)(r1 + (size_t)w  * C);
            const float4 dd = *(const float4*)(r1 + (size_t)w2 * C);
            mx = fmaxf(fmaxf(fmaxf(mx, a.x), fmaxf(bb.x, cc.x)), dd.x);
            my = fmaxf(fmaxf(fmaxf(my, a.y), fmaxf(bb.y, cc.y)), dd.y);
            mz = fmaxf(fmaxf(fmaxf(mz, a.z), fmaxf(bb.z, cc.z)), dd.z);
            mw = fmaxf(fmaxf(fmaxf(mw, a.w), fmaxf(bb.w, cc.w)), dd.w);
        }
    }
    o[0] = mx; o[PP] = my; o[2 * PP] = mz; o[3 * PP] = mw;
}

// ---------------------------------------------------------------------------
// Fallback tier 2: no workspace
// ---------------------------------------------------------------------------
__global__ __launch_bounds__(256) void roi_pool_naive_kernel(
    const float* __restrict__ features, const float* __restrict__ rois,
    float* __restrict__ out)
{
    const int rb = blockIdx.x;
    const int r = rb / P;
    const int i = rb % P;
    const int c = threadIdx.x;

    const float* roi = rois + (size_t)r * 5;
    const int b = (int)roi[0];
    int x0 = (int)rintf(roi[1] * 0.03125f);
    int y0 = (int)rintf(roi[2] * 0.03125f);
    int x1 = (int)rintf(roi[3] * 0.03125f);
    int y1 = (int)rintf(roi[4] * 0.03125f);
    x0 = min(max(x0, 0), W - 1);
    y0 = min(max(y0, 0), H - 1);
    x1 = min(max(x1, 0), W - 1);
    y1 = min(max(y1, 0), H - 1);

    const bool valid = (x0 < x1) && (y0 < y1);
    float* o = out + (((size_t)r * C + c) * P + i) * P;
    if (!valid) {
        #pragma unroll
        for (int j = 0; j < P; ++j) o[j] = 0.0f;
        return;
    }
    const int Lh = x1 - x0, Lw = y1 - y0;
    const int hs = x0 + (i * Lh) / P;
    const int he = x0 + ((i + 1) * Lh + (P - 1)) / P;
    int ws_[P], we_[P];
    #pragma unroll
    for (int j = 0; j < P; ++j) {
        ws_[j] = y0 + (j * Lw) / P;
        we_[j] = y0 + ((j + 1) * Lw + (P - 1)) / P;
    }
    float acc[P];
    #pragma unroll
    for (int j = 0; j < P; ++j) acc[j] = -INFINITY;
    const float* f = features + (((size_t)b * C + c) * H) * W;
    for (int h = hs; h < he; ++h) {
        const float* row = f + h * W;
        #pragma unroll
        for (int j = 0; j < P; ++j) {
            float m = acc[j];
            for (int w = ws_[j]; w < we_[j]; ++w) m = fmaxf(m, row[w]);
            acc[j] = m;
        }
    }
    #pragma unroll
    for (int j = 0; j < P; ++j) o[j] = acc[j];
}

extern "C" void kernel_launch(void* const* d_in, const int* in_sizes, int n_in,
                              void* d_out, int out_size, void* d_ws, size_t ws_size,
                              hipStream_t stream)
{
    const float* features = (const float*)d_in[0];
    const float* rois     = (const float*)d_in[1];
    float* out = (float*)d_out;

    const int R = in_sizes[1] / 5;                  // 256
    const int N = in_sizes[0] / (C * S);            // 4

    const size_t ft_bytes   = (size_t)N * C * S * sizeof(float);   // 16 MB
    const size_t perm_bytes = (size_t)R * sizeof(int);
    const size_t full_need  = ft_bytes + perm_bytes;

    if (ws_size >= full_need && R <= R_MAX) {
        float* ft  = (float*)d_ws;
        int*  perm = (int*)((char*)d_ws + ft_bytes);

        dim3 tgrid(S / TS, C / TS, N);
        transpose_kernel<<<tgrid, dim3(TS, 8), 0, stream>>>(features, ft);
        bucket_kernel<<<1, 256, 0, stream>>>(rois, perm, R);
        roi_pool_fused_kernel<<<R * NCG, 256, 0, stream>>>(ft, rois, perm, out);
    } else if (ws_size >= ft_bytes) {
        float* ft = (float*)d_ws;
        dim3 tgrid(S / TS, C / TS, N);
        transpose_kernel<<<tgrid, dim3(TS, 8), 0, stream>>>(features, ft);
        roi_pool_cell_direct_kernel<<<R * PP, 64, 0, stream>>>(ft, rois, out);
    } else {
        roi_pool_naive_kernel<<<R * P, C, 0, stream>>>(features, rois, out);
    }
}

// Round 10
// 38.182 us; speedup vs baseline: 1.7237x; 1.3004x over previous
//
#include <hip/hip_runtime.h>
#include <math.h>

#define P 7
#define PP (P * P)
#define C 256
#define H 64
#define W 64
#define S (H * W)
#define R_MAX 1024

#define NCP 25                // cell-pairs per roi (49 cells -> 25 pairs, last half-empty)
#define RPAD 257              // reorder LDS leading pad: [cell][channel<=255] needs >=256, +1 anti-conflict

// ---------------------------------------------------------------------------
// Transpose [N, C, S] -> [N, S, C], 64x64 tiles, float4 global on BOTH sides.
// Block (0,0,0) additionally computes the roi->slot permutation (stable
// counting sort by image id) -- runs concurrently with the other blocks,
// saving a dispatch.
// ---------------------------------------------------------------------------
#define TT 64
#define TPAD 65
__global__ __launch_bounds__(256) void transpose_bucket_kernel(
    const float* __restrict__ in, float* __restrict__ outT,
    const float* __restrict__ rois, int* __restrict__ perm, int R)
{
    __shared__ float tile[TT * TPAD];      // 16.6 KB
    const int b   = blockIdx.z;
    const int s0  = blockIdx.x * TT;
    const int c0  = blockIdx.y * TT;
    const int t   = threadIdx.x;
    const int r16 = t >> 4;                // 0..15
    const int m16 = (t & 15) * 4;          // 0,4,...,60

    #pragma unroll
    for (int k = 0; k < 4; ++k) {
        const int cl = r16 + 16 * k;
        const float4 v = *(const float4*)(in + (size_t)(b * C + c0 + cl) * S + s0 + m16);
        tile[cl * TPAD + m16 + 0] = v.x;
        tile[cl * TPAD + m16 + 1] = v.y;
        tile[cl * TPAD + m16 + 2] = v.z;
        tile[cl * TPAD + m16 + 3] = v.w;
    }
    __syncthreads();
    #pragma unroll
    for (int k = 0; k < 4; ++k) {
        const int sl = r16 + 16 * k;
        float4 v;
        v.x = tile[(m16 + 0) * TPAD + sl];
        v.y = tile[(m16 + 1) * TPAD + sl];
        v.z = tile[(m16 + 2) * TPAD + sl];
        v.w = tile[(m16 + 3) * TPAD + sl];
        *(float4*)(outT + (size_t)(b * S + s0 + sl) * C + c0 + m16) = v;
    }

    if (blockIdx.x == 0 && blockIdx.y == 0 && blockIdx.z == 0 && R > 0 && R <= R_MAX) {
        __shared__ int bimg[R_MAX];        // 4 KB
        for (int i = t; i < R; i += 256)
            bimg[i] = (int)rois[(size_t)i * 5];
        __syncthreads();
        for (int i = t; i < R; i += 256) {
            const int myb = bimg[i];
            int pos = 0;
            for (int k = 0; k < R; ++k) {
                const int bk = bimg[k];
                pos += (bk < myb) || (bk == myb && k < i);
            }
            perm[pos] = i;
        }
    }
}

// ---------------------------------------------------------------------------
// RoI max-pool: block = (rslot, cell-PAIR), 128 threads = 2 waves.
// Wave w owns cell 2*cp+w (uniform bin per wave -> no divergence), 64 lanes =
// 64 channel-quads = all 256 channels, 1KB contiguous per wave-load.
// 128-thr blocks dodge the 16-workgroup/CU cap: 16 WG x 2 waves = 32 waves/CU.
// Writes ws2[rslot, cell, C] contiguous. Chunked XCD swizzle + image-sorted
// rois keep each XCD on ~one 4MB image (L2-fit).
// ---------------------------------------------------------------------------
__global__ __launch_bounds__(128) void roi_pool_cell_kernel(
    const float* __restrict__ ft,    // [N, H, W, C]
    const float* __restrict__ rois,
    const int*   __restrict__ perm,
    float* __restrict__ ws2)         // [R, PP, C]
{
    const int l   = blockIdx.x;
    const int nwg = gridDim.x;            // R * NCP
    const int work  = ((nwg & 7) == 0) ? ((l & 7) * (nwg >> 3) + (l >> 3)) : l;
    const int rslot = work / NCP;
    const int cp    = work % NCP;
    const int cell  = 2 * cp + (threadIdx.x >> 6);
    const int q     = threadIdx.x & 63;   // channel quad 0..63

    if (cell >= PP) return;               // odd-count tail (wave-uniform)

    const int r = perm[rslot];
    const float* roi = rois + (size_t)r * 5;
    const int b = (int)roi[0];
    // jnp.round is half-to-even; rintf matches (RNE); *2^-5 scale is exact.
    int x0 = (int)rintf(roi[1] * 0.03125f);
    int y0 = (int)rintf(roi[2] * 0.03125f);
    int x1 = (int)rintf(roi[3] * 0.03125f);
    int y1 = (int)rintf(roi[4] * 0.03125f);
    x0 = min(max(x0, 0), W - 1);
    y0 = min(max(y0, 0), H - 1);
    x1 = min(max(x1, 0), W - 1);
    y1 = min(max(y1, 0), H - 1);

    float4* o = (float4*)(ws2 + ((size_t)rslot * PP + cell) * C) + q;

    if (!((x0 < x1) && (y0 < y1))) {
        *o = make_float4(0.0f, 0.0f, 0.0f, 0.0f);
        return;
    }

    const int Lh = x1 - x0;  // x-range bins the H axis (reference quirk)
    const int Lw = y1 - y0;  // y-range bins the W axis
    const int i  = cell / P;
    const int j  = cell - P * i;

    const int hs = x0 + (i * Lh) / P;
    const int he = x0 + ((i + 1) * Lh + (P - 1)) / P;
    const int ws = y0 + (j * Lw) / P;
    const int we = y0 + ((j + 1) * Lw + (P - 1)) / P;
    const int bh = he - hs;               // >= 1
    const int bw = we - ws;               // >= 1

    const float* base = ft + (((size_t)b * H + hs) * W + ws) * C + q * 4;

    float mx = -INFINITY, my = -INFINITY, mz = -INFINITY, mw = -INFINITY;
    for (int h = 0; h < bh; h += 2) {
        const int h2 = min(h + 1, bh - 1);       // clamp: dup row no-op for max
        const float* r0 = base + (size_t)h  * (W * C);
        const float* r1 = base + (size_t)h2 * (W * C);
        for (int w = 0; w < bw; w += 2) {
            const int w2 = min(w + 1, bw - 1);   // clamp: dup col no-op
            const float4 a  = *(const float4*)(r0 + (size_t)w  * C);
            const float4 bb = *(const float4*)(r0 + (size_t)w2 * C);
            const float4 cc = *(const float4*)(r1 + (size_t)w  * C);
            const float4 dd = *(const float4*)(r1 + (size_t)w2 * C);
            mx = fmaxf(fmaxf(fmaxf(mx, a.x), fmaxf(bb.x, cc.x)), dd.x);
            my = fmaxf(fmaxf(fmaxf(my, a.y), fmaxf(bb.y, cc.y)), dd.y);
            mz = fmaxf(fmaxf(fmaxf(mz, a.z), fmaxf(bb.z, cc.z)), dd.z);
            mw = fmaxf(fmaxf(fmaxf(mw, a.w), fmaxf(bb.w, cc.w)), dd.w);
        }
    }

    *o = make_float4(mx, my, mz, mw);
}

// ---------------------------------------------------------------------------
// Reorder ws2[rslot, cell, C] -> out[r, C, cell] via LDS; both sides
// coalesced, out written as full-line float4 stores. (R5 version, RPAD=257.)
// ---------------------------------------------------------------------------
__global__ __launch_bounds__(256) void reorder_kernel(
    const float* __restrict__ ws2,
    const int*   __restrict__ perm,
    float* __restrict__ out)         // [R, C, PP]
{
    __shared__ float lds[PP * RPAD];   // 49*257*4 = 50.4 KB
    const int l = blockIdx.x;
    const int R = gridDim.x;
    const int rslot = ((R & 7) == 0) ? ((l & 7) * (R >> 3) + (l >> 3)) : l;
    const int r = perm[rslot];
    const int tid = threadIdx.x;

    const float* src = ws2 + (size_t)rslot * PP * C;
    #pragma unroll
    for (int cell = 0; cell < PP; ++cell)
        lds[cell * RPAD + tid] = src[(size_t)cell * C + tid];

    __syncthreads();

    float* dst = out + (size_t)r * C * PP;
    const int nq = (C * PP) / 4;     // 3136 float4s
    #pragma unroll
    for (int k = 0; k < 13; ++k) {
        const int q = tid + 256 * k;
        if (q < nq) {
            float v[4];
            #pragma unroll
            for (int m = 0; m < 4; ++m) {
                const int idx  = 4 * q + m;
                const int c    = idx / PP;
                const int cell = idx % PP;
                v[m] = lds[cell * RPAD + c];
            }
            *(float4*)(dst + 4 * q) = make_float4(v[0], v[1], v[2], v[3]);
        }
    }
}

// ---------------------------------------------------------------------------
// Fallback tier 1: pool with direct strided out writes (no perm/ws2 needed)
// ---------------------------------------------------------------------------
__global__ __launch_bounds__(64) void roi_pool_cell_direct_kernel(
    const float* __restrict__ ft, const float* __restrict__ rois,
    float* __restrict__ out)
{
    const int bid = blockIdx.x;
    const int r   = bid / PP;
    const int rem = bid % PP;
    const int i   = rem / P;
    const int j   = rem % P;
    const int c4  = threadIdx.x;

    const float* roi = rois + (size_t)r * 5;
    const int b = (int)roi[0];
    int x0 = (int)rintf(roi[1] * 0.03125f);
    int y0 = (int)rintf(roi[2] * 0.03125f);
    int x1 = (int)rintf(roi[3] * 0.03125f);
    int y1 = (int)rintf(roi[4] * 0.03125f);
    x0 = min(max(x0, 0), W - 1);
    y0 = min(max(y0, 0), H - 1);
    x1 = min(max(x1, 0), W - 1);
    y1 = min(max(y1, 0), H - 1);

    float* o = out + (((size_t)r * C + c4 * 4) * P + i) * P + j;
    if (!((x0 < x1) && (y0 < y1))) {
        o[0] = 0.0f; o[PP] = 0.0f; o[2 * PP] = 0.0f; o[3 * PP] = 0.0f;
        return;
    }
    const int Lh = x1 - x0, Lw = y1 - y0;
    const int hs = x0 + (i * Lh) / P;
    const int he = x0 + ((i + 1) * Lh + (P - 1)) / P;
    const int ws = y0 + (j * Lw) / P;
    const int we = y0 + ((j + 1) * Lw + (P - 1)) / P;
    const int bh = he - hs, bw = we - ws;
    const float* base = ft + (((size_t)b * H + hs) * W + ws) * C + c4 * 4;
    float mx = -INFINITY, my = -INFINITY, mz = -INFINITY, mw = -INFINITY;
    for (int h = 0; h < bh; h += 2) {
        const int h2 = min(h + 1, bh - 1);
        const float* r0 = base + (size_t)h  * (W * C);
        const float* r1 = base + (size_t)h2 * (W * C);
        for (int w = 0; w < bw; w += 2) {
            const int w2 = min(w + 1, bw - 1);
            const float4 a  = *(const float4*)(r0 + (size_t)w  * C);
            const float4 bb = *(const float4*)(r0 + (size_t)w2 * C);
            const float4 cc = *(const float4*)(r1 + (size_t)w  * C);
            const float4 dd = *(const float4*)(r1 + (size_t)w2 * C);
            mx = fmaxf(fmaxf(fmaxf(mx, a.x), fmaxf(bb.x, cc.x)), dd.x);
            my = fmaxf(fmaxf(fmaxf(my, a.y), fmaxf(bb.y, cc.y)), dd.y);
            mz = fmaxf(fmaxf(fmaxf(mz, a.z), fmaxf(bb.z, cc.z)), dd.z);
            mw = fmaxf(fmaxf(fmaxf(mw, a.w), fmaxf(bb.w, cc.w)), dd.w);
        }
    }
    o[0] = mx; o[PP] = my; o[2 * PP] = mz; o[3 * PP] = mw;
}

// ---------------------------------------------------------------------------
// Fallback tier 2: no workspace
// ---------------------------------------------------------------------------
__global__ __launch_bounds__(256) void roi_pool_naive_kernel(
    const float* __restrict__ features, const float* __restrict__ rois,
    float* __restrict__ out)
{
    const int rb = blockIdx.x;
    const int r = rb / P;
    const int i = rb % P;
    const int c = threadIdx.x;

    const float* roi = rois + (size_t)r * 5;
    const int b = (int)roi[0];
    int x0 = (int)rintf(roi[1] * 0.03125f);
    int y0 = (int)rintf(roi[2] * 0.03125f);
    int x1 = (int)rintf(roi[3] * 0.03125f);
    int y1 = (int)rintf(roi[4] * 0.03125f);
    x0 = min(max(x0, 0), W - 1);
    y0 = min(max(y0, 0), H - 1);
    x1 = min(max(x1, 0), W - 1);
    y1 = min(max(y1, 0), H - 1);

    const bool valid = (x0 < x1) && (y0 < y1);
    float* o = out + (((size_t)r * C + c) * P + i) * P;
    if (!valid) {
        #pragma unroll
        for (int j = 0; j < P; ++j) o[j] = 0.0f;
        return;
    }
    const int Lh = x1 - x0, Lw = y1 - y0;
    const int hs = x0 + (i * Lh) / P;
    const int he = x0 + ((i + 1) * Lh + (P - 1)) / P;
    int ws_[P], we_[P];
    #pragma unroll
    for (int j = 0; j < P; ++j) {
        ws_[j] = y0 + (j * Lw) / P;
        we_[j] = y0 + ((j + 1) * Lw + (P - 1)) / P;
    }
    float acc[P];
    #pragma unroll
    for (int j = 0; j < P; ++j) acc[j] = -INFINITY;
    const float* f = features + (((size_t)b * C + c) * H) * W;
    for (int h = hs; h < he; ++h) {
        const float* row = f + h * W;
        #pragma unroll
        for (int j = 0; j < P; ++j) {
            float m = acc[j];
            for (int w = ws_[j]; w < we_[j]; ++w) m = fmaxf(m, row[w]);
            acc[j] = m;
        }
    }
    #pragma unroll
    for (int j = 0; j < P; ++j) o[j] = acc[j];
}

extern "C" void kernel_launch(void* const* d_in, const int* in_sizes, int n_in,
                              void* d_out, int out_size, void* d_ws, size_t ws_size,
                              hipStream_t stream)
{
    const float* features = (const float*)d_in[0];
    const float* rois     = (const float*)d_in[1];
    float* out = (float*)d_out;

    const int R = in_sizes[1] / 5;                  // 256
    const int N = in_sizes[0] / (C * S);            // 4

    const size_t ft_bytes   = (size_t)N * C * S * sizeof(float);   // 16 MB
    const size_t ws2_bytes  = (size_t)R * PP * C * sizeof(float);  // 12.8 MB
    const size_t perm_bytes = (size_t)R * sizeof(int);
    const size_t full_need  = ft_bytes + ws2_bytes + perm_bytes;

    if (ws_size >= full_need && R <= R_MAX) {
        float* ft  = (float*)d_ws;
        float* ws2 = (float*)((char*)d_ws + ft_bytes);
        int*  perm = (int*)((char*)d_ws + ft_bytes + ws2_bytes);

        dim3 tgrid(S / TT, C / TT, N);              // 64 x 4 x 4 = 1024 blocks
        transpose_bucket_kernel<<<tgrid, 256, 0, stream>>>(features, ft, rois, perm, R);
        roi_pool_cell_kernel<<<R * NCP, 128, 0, stream>>>(ft, rois, perm, ws2);
        reorder_kernel<<<R, 256, 0, stream>>>(ws2, perm, out);
    } else if (ws_size >= ft_bytes) {
        float* ft = (float*)d_ws;
        dim3 tgrid(S / TT, C / TT, N);
        transpose_bucket_kernel<<<tgrid, 256, 0, stream>>>(features, ft, rois, (int*)nullptr, 0);
        roi_pool_cell_direct_kernel<<<R * PP, 64, 0, stream>>>(ft, rois, out);
    } else {
        roi_pool_naive_kernel<<<R * P, C, 0, stream>>>(features, rois, out);
    }
}